// Round 1
// baseline (1144.486 us; speedup 1.0000x reference)
//
#include <hip/hip_runtime.h>
#include <hip/hip_bf16.h>

#define B  2
#define NN_ 5000
#define NE_ 160000
#define F  128
#define HID 128
#define ED 16
#define IN_EDGE 288   // 2*F + 16 + ED

#define EPB 8   // edges per block (edge kernel)
#define NPB 8   // nodes per block (node kernel)

__global__ __launch_bounds__(128) void edge_kernel(
    const float* __restrict__ h, const float* __restrict__ coord,
    const int* __restrict__ ei, const float* __restrict__ ea,
    const float* __restrict__ We1, const float* __restrict__ be1,
    const float* __restrict__ We2, const float* __restrict__ be2,
    const float* __restrict__ Wc1, const float* __restrict__ bc1,
    const float* __restrict__ Wc2,
    float* __restrict__ agg_h, float* __restrict__ agg_c, float* __restrict__ cnt)
{
    __shared__ float xs[EPB][IN_EDGE];   // gathered edge input
    __shared__ float cds[EPB][12];       // coord diffs
    __shared__ float h1[EPB][HID];       // hidden buffer (reused)
    __shared__ float efs[EPB][HID];      // ef (edge features)
    __shared__ float wcs[EPB][4];        // coord weights
    __shared__ int rs[EPB], cs[EPB];

    const int t  = threadIdx.x;       // 0..127, output column
    const int b  = blockIdx.y;
    const int e0 = blockIdx.x * EPB;

    if (t < EPB) { rs[t] = ei[e0 + t]; cs[t] = ei[NE_ + e0 + t]; }
    __syncthreads();

    // ---- stage x: [h_row | h_col | radial | edge_attr] ----
    const float* hb = h + (size_t)b * NN_ * F;
    #pragma unroll
    for (int e = 0; e < EPB; e++) {
        xs[e][t]     = hb[rs[e] * F + t];
        xs[e][F + t] = hb[cs[e] * F + t];
    }
    {   // edge_attr: 8 edges * 16 = 128 values
        int e = t >> 4, j = t & 15;
        xs[e][2 * F + 16 + j] = ea[(e0 + e) * ED + j];
    }
    if (t < EPB) {   // cd + radial (one thread per edge, small serial work)
        int e = t;
        const float* cr = coord + ((size_t)b * NN_ + rs[e]) * 12;
        const float* cc = coord + ((size_t)b * NN_ + cs[e]) * 12;
        float cd[12];
        #pragma unroll
        for (int j = 0; j < 12; j++) { cd[j] = cr[j] - cc[j]; cds[e][j] = cd[j]; }
        float prod[16]; float ss = 0.f;
        #pragma unroll
        for (int j = 0; j < 4; j++)
            #pragma unroll
            for (int k = 0; k < 4; k++) {
                float p = cd[j*3]*cd[k*3] + cd[j*3+1]*cd[k*3+1] + cd[j*3+2]*cd[k*3+2];
                prod[j*4 + k] = p; ss += p * p;
            }
        float inv = 1.0f / fmaxf(sqrtf(ss), 1e-12f);
        #pragma unroll
        for (int j = 0; j < 16; j++) xs[e][2 * F + j] = prod[j] * inv;
    }
    __syncthreads();

    // ---- layer e1: x(288) @ We1 -> relu -> h1 ----
    float acc[EPB];
    #pragma unroll
    for (int e = 0; e < EPB; e++) acc[e] = be1[t];
    for (int k = 0; k < IN_EDGE; k += 4) {
        float w0 = We1[(k+0)*HID + t], w1 = We1[(k+1)*HID + t];
        float w2 = We1[(k+2)*HID + t], w3 = We1[(k+3)*HID + t];
        #pragma unroll
        for (int e = 0; e < EPB; e++) {
            float4 xv = *(const float4*)&xs[e][k];
            acc[e] += xv.x*w0 + xv.y*w1 + xv.z*w2 + xv.w*w3;
        }
    }
    __syncthreads();
    #pragma unroll
    for (int e = 0; e < EPB; e++) h1[e][t] = fmaxf(acc[e], 0.f);
    __syncthreads();

    // ---- layer e2: h1 @ We2 -> relu -> ef ----
    float efr[EPB];
    #pragma unroll
    for (int e = 0; e < EPB; e++) acc[e] = be2[t];
    for (int k = 0; k < HID; k += 4) {
        float w0 = We2[(k+0)*HID + t], w1 = We2[(k+1)*HID + t];
        float w2 = We2[(k+2)*HID + t], w3 = We2[(k+3)*HID + t];
        #pragma unroll
        for (int e = 0; e < EPB; e++) {
            float4 xv = *(const float4*)&h1[e][k];
            acc[e] += xv.x*w0 + xv.y*w1 + xv.z*w2 + xv.w*w3;
        }
    }
    __syncthreads();
    #pragma unroll
    for (int e = 0; e < EPB; e++) { efr[e] = fmaxf(acc[e], 0.f); efs[e][t] = efr[e]; }
    __syncthreads();

    // ---- coord layer c1: ef @ Wc1 -> relu -> h1 (reused) ----
    #pragma unroll
    for (int e = 0; e < EPB; e++) acc[e] = bc1[t];
    for (int k = 0; k < HID; k += 4) {
        float w0 = Wc1[(k+0)*HID + t], w1 = Wc1[(k+1)*HID + t];
        float w2 = Wc1[(k+2)*HID + t], w3 = Wc1[(k+3)*HID + t];
        #pragma unroll
        for (int e = 0; e < EPB; e++) {
            float4 xv = *(const float4*)&efs[e][k];
            acc[e] += xv.x*w0 + xv.y*w1 + xv.z*w2 + xv.w*w3;
        }
    }
    __syncthreads();
    #pragma unroll
    for (int e = 0; e < EPB; e++) h1[e][t] = fmaxf(acc[e], 0.f);
    __syncthreads();

    // ---- coord layer c2: h1 @ Wc2(128x4), no bias ----
    if (t < EPB * 4) {
        int e = t >> 2, j = t & 3;
        float a = 0.f;
        for (int k = 0; k < HID; k++) a += h1[e][k] * Wc2[k * 4 + j];
        wcs[e][j] = a;
    }
    __syncthreads();

    // ---- scatter: agg_h += ef, agg_c += cd*w, cnt += 1 ----
    float* aggh_b = agg_h + (size_t)b * NN_ * HID;
    #pragma unroll
    for (int e = 0; e < EPB; e++)
        atomicAdd(&aggh_b[rs[e] * HID + t], efr[e]);
    if (t < EPB * 12) {
        int e = t / 12, j = t % 12;
        float val = cds[e][j] * wcs[e][j / 3];
        atomicAdd(&agg_c[((size_t)b * NN_ + rs[e]) * 12 + j], val);
    }
    if (t < EPB)
        atomicAdd(&cnt[b * NN_ + rs[t]], 1.0f);
}

__global__ __launch_bounds__(128) void node_kernel(
    const float* __restrict__ h, const float* __restrict__ agg_h,
    const float* __restrict__ Wn1, const float* __restrict__ bn1,
    const float* __restrict__ Wn2, const float* __restrict__ bn2,
    float* __restrict__ out_h)
{
    __shared__ float zs[NPB][2 * F];
    __shared__ float h1[NPB][HID];
    const int t  = threadIdx.x;
    const int b  = blockIdx.y;
    const int n0 = blockIdx.x * NPB;

    #pragma unroll
    for (int i = 0; i < NPB; i++) {
        size_t base = ((size_t)b * NN_ + n0 + i);
        zs[i][t]     = h[base * F + t];
        zs[i][F + t] = agg_h[base * HID + t];
    }
    __syncthreads();

    float acc[NPB];
    #pragma unroll
    for (int i = 0; i < NPB; i++) acc[i] = bn1[t];
    for (int k = 0; k < 2 * F; k += 4) {
        float w0 = Wn1[(k+0)*HID + t], w1 = Wn1[(k+1)*HID + t];
        float w2 = Wn1[(k+2)*HID + t], w3 = Wn1[(k+3)*HID + t];
        #pragma unroll
        for (int i = 0; i < NPB; i++) {
            float4 xv = *(const float4*)&zs[i][k];
            acc[i] += xv.x*w0 + xv.y*w1 + xv.z*w2 + xv.w*w3;
        }
    }
    __syncthreads();
    #pragma unroll
    for (int i = 0; i < NPB; i++) h1[i][t] = fmaxf(acc[i], 0.f);
    __syncthreads();

    #pragma unroll
    for (int i = 0; i < NPB; i++) acc[i] = bn2[t];
    for (int k = 0; k < HID; k += 4) {
        float w0 = Wn2[(k+0)*F + t], w1 = Wn2[(k+1)*F + t];
        float w2 = Wn2[(k+2)*F + t], w3 = Wn2[(k+3)*F + t];
        #pragma unroll
        for (int i = 0; i < NPB; i++) {
            float4 xv = *(const float4*)&h1[i][k];
            acc[i] += xv.x*w0 + xv.y*w1 + xv.z*w2 + xv.w*w3;
        }
    }
    #pragma unroll
    for (int i = 0; i < NPB; i++) {
        size_t base = ((size_t)b * NN_ + n0 + i);
        out_h[base * F + t] = zs[i][t] + acc[i];
    }
}

__global__ void coord_kernel(
    const float* __restrict__ coord, const float* __restrict__ agg_c,
    const float* __restrict__ cnt, float* __restrict__ out_c)
{
    int i = blockIdx.x * 256 + threadIdx.x;
    if (i < B * NN_ * 12) {
        int node = i / 12;   // b*N + n
        out_c[i] = coord[i] + agg_c[i] / fmaxf(cnt[node], 1.0f);
    }
}

extern "C" void kernel_launch(void* const* d_in, const int* in_sizes, int n_in,
                              void* d_out, int out_size, void* d_ws, size_t ws_size,
                              hipStream_t stream) {
    const float* h     = (const float*)d_in[0];
    const float* coord = (const float*)d_in[1];
    const int*   ei    = (const int*)d_in[2];
    const float* ea    = (const float*)d_in[3];
    const float* We1   = (const float*)d_in[4];
    const float* be1   = (const float*)d_in[5];
    const float* We2   = (const float*)d_in[6];
    const float* be2   = (const float*)d_in[7];
    const float* Wn1   = (const float*)d_in[8];
    const float* bn1   = (const float*)d_in[9];
    const float* Wn2   = (const float*)d_in[10];
    const float* bn2   = (const float*)d_in[11];
    const float* Wc1   = (const float*)d_in[12];
    const float* bc1   = (const float*)d_in[13];
    const float* Wc2   = (const float*)d_in[14];

    float* out_h = (float*)d_out;                       // [B,N,F]
    float* out_c = out_h + (size_t)B * NN_ * F;         // [B,N,4,3]

    float* agg_h = (float*)d_ws;                        // [B,N,HID]
    float* agg_c = agg_h + (size_t)B * NN_ * HID;       // [B,N,12]
    float* cnt   = agg_c + (size_t)B * NN_ * 12;        // [B,N]

    size_t zero_bytes = ((size_t)B * NN_ * (HID + 12 + 1)) * sizeof(float);
    hipMemsetAsync(d_ws, 0, zero_bytes, stream);

    dim3 eg(NE_ / EPB, B);   // 20000 x 2
    edge_kernel<<<eg, 128, 0, stream>>>(h, coord, ei, ea,
                                        We1, be1, We2, be2, Wc1, bc1, Wc2,
                                        agg_h, agg_c, cnt);

    dim3 ng(NN_ / NPB, B);   // 625 x 2
    node_kernel<<<ng, 128, 0, stream>>>(h, agg_h, Wn1, bn1, Wn2, bn2, out_h);

    int cn = (B * NN_ * 12 + 255) / 256;
    coord_kernel<<<cn, 256, 0, stream>>>(coord, agg_c, cnt, out_c);
}

// Round 2
// 397.791 us; speedup vs baseline: 2.8771x; 2.8771x over previous
//
#include <hip/hip_runtime.h>
#include <hip/hip_bf16.h>

#define B   2
#define NN_ 5000
#define NE_ 160000
#define F   128
#define HID 128
#define ED  16
#define IN_EDGE 288   // 2*F + 16 + ED

typedef __bf16 bf16x8 __attribute__((ext_vector_type(8)));
typedef __bf16 bf16x4 __attribute__((ext_vector_type(4)));
typedef float  f32x4  __attribute__((ext_vector_type(4)));

#define XSS 296   // xs row stride (bf16 elems): 16B-aligned rows, 2-way banks (free)
#define MS  136   // mid-buffer row stride

// ---------------- weight pack: row-major fp32 [K][N] -> bf16 MFMA B-fragments ----
// frag layout (16x16x32): lane l holds B[k = kt*32 + (l>>4)*8 + j][n = nt*16 + (l&15)]
// packed[( (nt*KT + kt)*64 + lane )*8 + j]
__global__ void pack_weights(const float* __restrict__ We1, const float* __restrict__ We2,
                             const float* __restrict__ Wc1, const float* __restrict__ Wc2,
                             __bf16* __restrict__ pw1, __bf16* __restrict__ pw2,
                             __bf16* __restrict__ pwc1, __bf16* __restrict__ pwc2)
{
    int idx = blockIdx.x * 256 + threadIdx.x;   // 0 .. 71679
    const float* W; __bf16* P; int KT, Nr, local;
    if (idx < 36864)      { W = We1; P = pw1;  KT = 9; Nr = 128; local = idx; }
    else if (idx < 53248) { W = We2; P = pw2;  KT = 4; Nr = 128; local = idx - 36864; }
    else if (idx < 69632) { W = Wc1; P = pwc1; KT = 4; Nr = 128; local = idx - 53248; }
    else                  { W = Wc2; P = pwc2; KT = 4; Nr = 4;   local = idx - 69632; }
    int j = local & 7, lane = (local >> 3) & 63, rest = local >> 9;
    int kt = rest % KT, nt = rest / KT;
    int k = kt * 32 + (lane >> 4) * 8 + j;
    int n = nt * 16 + (lane & 15);
    float v = (n < Nr) ? W[k * Nr + n] : 0.f;
    P[local] = (__bf16)v;
}

// ---------------- edge kernel: gather -> 4-layer MFMA MLP -> scatter ----------
__global__ __launch_bounds__(256) void edge_kernel(
    const float* __restrict__ h, const float* __restrict__ coord,
    const int* __restrict__ ei, const float* __restrict__ ea,
    const float* __restrict__ be1, const float* __restrict__ be2,
    const float* __restrict__ bc1,
    const __bf16* __restrict__ pw1, const __bf16* __restrict__ pw2,
    const __bf16* __restrict__ pwc1, const __bf16* __restrict__ pwc2,
    float* __restrict__ agg_h, float* __restrict__ agg_c, float* __restrict__ cnt)
{
    __shared__ __align__(16) __bf16 R[18944];        // xs[64][296] | buf1/buf2[64][136]
    __shared__ float cds[64][12];
    __shared__ int rs[64], cs[64];

    const int t = threadIdx.x;
    const int b = blockIdx.y;
    const int e0 = blockIdx.x * 64;
    const int lane = t & 63, wave = t >> 6;
    const int quad = lane >> 4, c = lane & 15;

    if (t < 64) { rs[t] = ei[e0 + t]; cs[t] = ei[NE_ + e0 + t]; }
    __syncthreads();

    // ---- stage xs = [h_row | h_col | radial | edge_attr] as bf16 ----
    const float* hb = h + (size_t)b * NN_ * F;
    #pragma unroll
    for (int eb = 0; eb < 64; eb += 4) {
        int e = eb + wave;
        int node, dst;
        if (lane < 32) { node = rs[e]; dst = lane * 4; }
        else           { node = cs[e]; dst = F + (lane - 32) * 4; }
        float4 v = *(const float4*)(hb + (size_t)node * F + (lane & 31) * 4);
        bf16x4 bv = { (__bf16)v.x, (__bf16)v.y, (__bf16)v.z, (__bf16)v.w };
        *(bf16x4*)&R[e * XSS + dst] = bv;
    }
    if (t < 64) {
        int e = t;
        const float* cr = coord + ((size_t)b * NN_ + rs[e]) * 12;
        const float* cc = coord + ((size_t)b * NN_ + cs[e]) * 12;
        float cd[12];
        #pragma unroll
        for (int j = 0; j < 12; j++) { cd[j] = cr[j] - cc[j]; cds[e][j] = cd[j]; }
        float prod[16]; float ss = 0.f;
        #pragma unroll
        for (int j = 0; j < 4; j++)
            #pragma unroll
            for (int k = 0; k < 4; k++) {
                float p = cd[j*3]*cd[k*3] + cd[j*3+1]*cd[k*3+1] + cd[j*3+2]*cd[k*3+2];
                prod[j*4 + k] = p; ss += p * p;
            }
        float inv = 1.0f / fmaxf(sqrtf(ss), 1e-12f);
        #pragma unroll
        for (int j = 0; j < 16; j++) R[e * XSS + 2*F + j] = (__bf16)(prod[j] * inv);
        const float* eap = ea + (size_t)(e0 + e) * ED;
        #pragma unroll
        for (int j = 0; j < 16; j++) R[e * XSS + 2*F + 16 + j] = (__bf16)eap[j];
    }
    __syncthreads();

    const bf16x8* pw1v  = (const bf16x8*)pw1;
    const bf16x8* pw2v  = (const bf16x8*)pw2;
    const bf16x8* pwc1v = (const bf16x8*)pwc1;
    const bf16x8* pwc2v = (const bf16x8*)pwc2;
    __bf16* buf1 = R;
    __bf16* buf2 = R + 8704;   // 64*136

    // ---- layer e1: x(288) @ We1 ----
    f32x4 acc[8];
    #pragma unroll
    for (int nt = 0; nt < 8; nt++) acc[nt] = (f32x4){0.f, 0.f, 0.f, 0.f};
    for (int kt = 0; kt < 9; kt++) {
        bf16x8 a = *(const bf16x8*)&R[(wave*16 + c) * XSS + kt*32 + quad*8];
        #pragma unroll
        for (int nt = 0; nt < 8; nt++)
            acc[nt] = __builtin_amdgcn_mfma_f32_16x16x32_bf16(a, pw1v[(nt*9 + kt)*64 + lane], acc[nt], 0, 0, 0);
    }
    __syncthreads();   // xs dead everywhere; R reusable
    #pragma unroll
    for (int nt = 0; nt < 8; nt++)
        #pragma unroll
        for (int i = 0; i < 4; i++) {
            float v = fmaxf(acc[nt][i] + be1[nt*16 + c], 0.f);
            buf1[(wave*16 + quad*4 + i) * MS + nt*16 + c] = (__bf16)v;
        }
    __syncthreads();

    // ---- layer e2: h1 @ We2 -> ef ----
    f32x4 acc2[8];
    #pragma unroll
    for (int nt = 0; nt < 8; nt++) acc2[nt] = (f32x4){0.f, 0.f, 0.f, 0.f};
    for (int kt = 0; kt < 4; kt++) {
        bf16x8 a = *(const bf16x8*)&buf1[(wave*16 + c) * MS + kt*32 + quad*8];
        #pragma unroll
        for (int nt = 0; nt < 8; nt++)
            acc2[nt] = __builtin_amdgcn_mfma_f32_16x16x32_bf16(a, pw2v[(nt*4 + kt)*64 + lane], acc2[nt], 0, 0, 0);
    }
    int er[4];
    #pragma unroll
    for (int i = 0; i < 4; i++) er[i] = rs[wave*16 + quad*4 + i];
    float* aggh_b = agg_h + (size_t)b * NN_ * HID;
    #pragma unroll
    for (int nt = 0; nt < 8; nt++)
        #pragma unroll
        for (int i = 0; i < 4; i++) {
            float v = fmaxf(acc2[nt][i] + be2[nt*16 + c], 0.f);
            atomicAdd(&aggh_b[(size_t)er[i] * HID + nt*16 + c], v);
            buf2[(wave*16 + quad*4 + i) * MS + nt*16 + c] = (__bf16)v;
        }
    __syncthreads();

    // ---- coord layer c1: ef @ Wc1 ----
    f32x4 acc3[8];
    #pragma unroll
    for (int nt = 0; nt < 8; nt++) acc3[nt] = (f32x4){0.f, 0.f, 0.f, 0.f};
    for (int kt = 0; kt < 4; kt++) {
        bf16x8 a = *(const bf16x8*)&buf2[(wave*16 + c) * MS + kt*32 + quad*8];
        #pragma unroll
        for (int nt = 0; nt < 8; nt++)
            acc3[nt] = __builtin_amdgcn_mfma_f32_16x16x32_bf16(a, pwc1v[(nt*4 + kt)*64 + lane], acc3[nt], 0, 0, 0);
    }
    __syncthreads();
    #pragma unroll
    for (int nt = 0; nt < 8; nt++)
        #pragma unroll
        for (int i = 0; i < 4; i++) {
            float v = fmaxf(acc3[nt][i] + bc1[nt*16 + c], 0.f);
            buf1[(wave*16 + quad*4 + i) * MS + nt*16 + c] = (__bf16)v;
        }
    __syncthreads();

    // ---- coord layer c2: h2 @ Wc2 (128x4, padded to 16 cols) ----
    f32x4 accw = (f32x4){0.f, 0.f, 0.f, 0.f};
    for (int kt = 0; kt < 4; kt++) {
        bf16x8 a = *(const bf16x8*)&buf1[(wave*16 + c) * MS + kt*32 + quad*8];
        accw = __builtin_amdgcn_mfma_f32_16x16x32_bf16(a, pwc2v[kt*64 + lane], accw, 0, 0, 0);
    }
    // ---- scatter trans & cnt ----
    if (c < 4) {
        #pragma unroll
        for (int i = 0; i < 4; i++) {
            float w = accw[i];
            int el = wave*16 + quad*4 + i;
            float* dst = agg_c + ((size_t)b * NN_ + er[i]) * 12 + c*3;
            #pragma unroll
            for (int d = 0; d < 3; d++)
                atomicAdd(&dst[d], cds[el][c*3 + d] * w);
        }
    }
    if (c == 0) {
        #pragma unroll
        for (int i = 0; i < 4; i++)
            atomicAdd(&cnt[b * NN_ + er[i]], 1.0f);
    }
}

// ---------------- node kernel (fp32, unchanged) ----------------
#define NPB 8
__global__ __launch_bounds__(128) void node_kernel(
    const float* __restrict__ h, const float* __restrict__ agg_h,
    const float* __restrict__ Wn1, const float* __restrict__ bn1,
    const float* __restrict__ Wn2, const float* __restrict__ bn2,
    float* __restrict__ out_h)
{
    __shared__ float zs[NPB][2 * F];
    __shared__ float h1[NPB][HID];
    const int t  = threadIdx.x;
    const int b  = blockIdx.y;
    const int n0 = blockIdx.x * NPB;

    #pragma unroll
    for (int i = 0; i < NPB; i++) {
        size_t base = ((size_t)b * NN_ + n0 + i);
        zs[i][t]     = h[base * F + t];
        zs[i][F + t] = agg_h[base * HID + t];
    }
    __syncthreads();

    float acc[NPB];
    #pragma unroll
    for (int i = 0; i < NPB; i++) acc[i] = bn1[t];
    for (int k = 0; k < 2 * F; k += 4) {
        float w0 = Wn1[(k+0)*HID + t], w1 = Wn1[(k+1)*HID + t];
        float w2 = Wn1[(k+2)*HID + t], w3 = Wn1[(k+3)*HID + t];
        #pragma unroll
        for (int i = 0; i < NPB; i++) {
            float4 xv = *(const float4*)&zs[i][k];
            acc[i] += xv.x*w0 + xv.y*w1 + xv.z*w2 + xv.w*w3;
        }
    }
    __syncthreads();
    #pragma unroll
    for (int i = 0; i < NPB; i++) h1[i][t] = fmaxf(acc[i], 0.f);
    __syncthreads();

    #pragma unroll
    for (int i = 0; i < NPB; i++) acc[i] = bn2[t];
    for (int k = 0; k < HID; k += 4) {
        float w0 = Wn2[(k+0)*F + t], w1 = Wn2[(k+1)*F + t];
        float w2 = Wn2[(k+2)*F + t], w3 = Wn2[(k+3)*F + t];
        #pragma unroll
        for (int i = 0; i < NPB; i++) {
            float4 xv = *(const float4*)&h1[i][k];
            acc[i] += xv.x*w0 + xv.y*w1 + xv.z*w2 + xv.w*w3;
        }
    }
    #pragma unroll
    for (int i = 0; i < NPB; i++) {
        size_t base = ((size_t)b * NN_ + n0 + i);
        out_h[base * F + t] = zs[i][t] + acc[i];
    }
}

__global__ void coord_kernel(
    const float* __restrict__ coord, const float* __restrict__ agg_c,
    const float* __restrict__ cnt, float* __restrict__ out_c)
{
    int i = blockIdx.x * 256 + threadIdx.x;
    if (i < B * NN_ * 12) {
        int node = i / 12;
        out_c[i] = coord[i] + agg_c[i] / fmaxf(cnt[node], 1.0f);
    }
}

extern "C" void kernel_launch(void* const* d_in, const int* in_sizes, int n_in,
                              void* d_out, int out_size, void* d_ws, size_t ws_size,
                              hipStream_t stream) {
    const float* h     = (const float*)d_in[0];
    const float* coord = (const float*)d_in[1];
    const int*   ei    = (const int*)d_in[2];
    const float* ea    = (const float*)d_in[3];
    const float* We1   = (const float*)d_in[4];
    const float* be1   = (const float*)d_in[5];
    const float* We2   = (const float*)d_in[6];
    const float* be2   = (const float*)d_in[7];
    const float* Wn1   = (const float*)d_in[8];
    const float* bn1   = (const float*)d_in[9];
    const float* Wn2   = (const float*)d_in[10];
    const float* bn2   = (const float*)d_in[11];
    const float* Wc1   = (const float*)d_in[12];
    const float* bc1   = (const float*)d_in[13];
    const float* Wc2   = (const float*)d_in[14];

    float* out_h = (float*)d_out;                       // [B,N,F]
    float* out_c = out_h + (size_t)B * NN_ * F;         // [B,N,4,3]

    float* agg_h = (float*)d_ws;                        // [B,N,HID]
    float* agg_c = agg_h + (size_t)B * NN_ * HID;       // [B,N,12]
    float* cnt   = agg_c + (size_t)B * NN_ * 12;        // [B,N]
    __bf16* pw1  = (__bf16*)(cnt + (size_t)B * NN_);    // packed bf16 weights
    __bf16* pw2  = pw1 + 36864;
    __bf16* pwc1 = pw2 + 16384;
    __bf16* pwc2 = pwc1 + 16384;                        // +2048

    size_t zero_bytes = ((size_t)B * NN_ * (HID + 12 + 1)) * sizeof(float);
    hipMemsetAsync(d_ws, 0, zero_bytes, stream);

    pack_weights<<<280, 256, 0, stream>>>(We1, We2, Wc1, Wc2, pw1, pw2, pwc1, pwc2);

    dim3 eg(NE_ / 64, B);   // 2500 x 2
    edge_kernel<<<eg, 256, 0, stream>>>(h, coord, ei, ea, be1, be2, bc1,
                                        pw1, pw2, pwc1, pwc2,
                                        agg_h, agg_c, cnt);

    dim3 ng(NN_ / NPB, B);  // 625 x 2
    node_kernel<<<ng, 128, 0, stream>>>(h, agg_h, Wn1, bn1, Wn2, bn2, out_h);

    int cn = (B * NN_ * 12 + 255) / 256;
    coord_kernel<<<cn, 256, 0, stream>>>(coord, agg_c, cnt, out_c);
}